// Round 11
// baseline (304.285 us; speedup 1.0000x reference)
//
#include <hip/hip_runtime.h>
#include <hip/hip_bf16.h>
#include <math.h>

// Problem: B=4, T=2048, C=1024, H=16, D=64, d_half=32
// Dataflow:
//   cast x, w_attn, w_proj -> bf16
//   qkvb = xb @ wab^T  rope+rmsnorm fused into q/k epilogue; v written
//          PRE-TRANSPOSED to vt[b*C + h*64 + d][t] (packed short4 over r)
//   attn (bf16 MFMA flash, fixed-max softmax): QBLK=128/block, 2 subtiles
//          per wave, swapped QK^T keeps P in registers, ones-column row
//          sums, double-buffered staging, launch_bounds(256,3) (no spills).
//   out  = (qkvb v-cols as y, lda=3072) @ wpb^T  (fp32 out)
//   BOTH GEMMs: 128x256 block tile, per-wave 64x128 output (4x8 frags) —
//   25% fewer ds_read/FLOP than 64x64 (the serialized-pipe sum was the
//   R10 ceiling); 3-buffer counted-vmcnt(6) prefetch kept.

#define TT 2048
#define CC 1024
#define HH 16
#define DD 64

typedef __attribute__((ext_vector_type(8))) short short8;
typedef __attribute__((ext_vector_type(4))) short short4_t;
typedef __attribute__((ext_vector_type(4))) float f32x4;
typedef unsigned short ushort_t;

// fp32 -> bf16 (RNE, finite inputs only)
__device__ __forceinline__ ushort_t f2bf(float f) {
    unsigned u = __builtin_bit_cast(unsigned, f);
    u = (u + 0x7fffu + ((u >> 16) & 1u)) >> 16;
    return (ushort_t)u;
}

#define GLOAD_LDS(gp, lp)                                                      \
    __builtin_amdgcn_global_load_lds(                                          \
        (const __attribute__((address_space(1))) unsigned int*)(gp),           \
        (__attribute__((address_space(3))) unsigned int*)(lp), 16, 0, 0)

// ---------------------------------------------------------------------------
// float -> bf16 cast, 8 elements/thread
// ---------------------------------------------------------------------------
__global__ __launch_bounds__(256) void cast_bf16(const float* __restrict__ in,
                                                 ushort_t* __restrict__ out, int n8) {
    const int i = blockIdx.x * 256 + threadIdx.x;
    if (i >= n8) return;
    const float4* p = (const float4*)in + (size_t)i * 2;
    float4 f0 = p[0], f1 = p[1];
    short8 v;
    v[0] = (short)f2bf(f0.x); v[1] = (short)f2bf(f0.y);
    v[2] = (short)f2bf(f0.z); v[3] = (short)f2bf(f0.w);
    v[4] = (short)f2bf(f1.x); v[5] = (short)f2bf(f1.y);
    v[6] = (short)f2bf(f1.z); v[7] = (short)f2bf(f1.w);
    *(short8*)(out + (size_t)i * 8) = v;
}

// ---------------------------------------------------------------------------
// bf16 MFMA GEMM: C = A[M,K](lda) * B[N,K]^T, 128x256 tile, BK=32.
// Per wave 64x128 output (4x8 fragments). 3-buffer counted-vmcnt prefetch.
// ---------------------------------------------------------------------------
template <bool OUTF32>
__global__ __launch_bounds__(256) void gemm_bt(const ushort_t* __restrict__ A,
                                               const ushort_t* __restrict__ B,
                                               void* __restrict__ C,
                                               int M, int N, int K, int lda) {
    __shared__ ushort_t As[3][128 * 32];
    __shared__ ushort_t Bs[3][256 * 32];

    const int tid  = threadIdx.x;
    const int wv   = tid >> 6;
    const int ln   = tid & 63;
    const int quad = ln >> 4;
    const int lm   = ln & 15;
    const int wm   = wv & 1;
    const int wn   = wv >> 1;            // 0..1, 128 cols each
    const int rowC = blockIdx.y * 128;
    const int colC = blockIdx.x * 256;

    const int srow = wv * 16 + (ln >> 2);
    const int skq  = (ln & 3) * 8;

    f32x4 acc[4][8];
#pragma unroll
    for (int i = 0; i < 4; ++i)
#pragma unroll
        for (int j = 0; j < 8; ++j) acc[i][j] = (f32x4){0.f, 0.f, 0.f, 0.f};

    // 6 global_load_lds per thread per stage (A:2, B:4)
    auto stage = [&](int k0, int bufi) {
#pragma unroll
        for (int half = 0; half < 2; ++half) {
            const ushort_t* gA = A + (size_t)(rowC + half * 64 + srow) * lda + k0 + skq;
            GLOAD_LDS(gA, As[bufi] + (half * 64 + wv * 16) * 32);
        }
#pragma unroll
        for (int qtr = 0; qtr < 4; ++qtr) {
            const ushort_t* gB = B + (size_t)(colC + qtr * 64 + srow) * K + k0 + skq;
            GLOAD_LDS(gB, Bs[bufi] + (qtr * 64 + wv * 16) * 32);
        }
    };

    const int nk = K >> 5;
    stage(0, 0);
    stage(32, 1);
    asm volatile("s_waitcnt vmcnt(6)" ::: "memory");   // stage 0 complete
    __builtin_amdgcn_sched_barrier(0);
    __builtin_amdgcn_s_barrier();

    int cur = 0;
    for (int ki = 0; ki < nk; ++ki) {
        const bool has2 = (ki + 2 < nk);
        if (has2) {
            int b2 = cur + 2; if (b2 >= 3) b2 -= 3;
            stage((ki + 2) << 5, b2);                  // issue 2-ahead
        }

        short8 af[4], bf[8];
#pragma unroll
        for (int mt = 0; mt < 4; ++mt)
            af[mt] = *(const short8*)&As[cur][(wm * 64 + mt * 16 + lm) * 32 + quad * 8];
#pragma unroll
        for (int nt = 0; nt < 8; ++nt)
            bf[nt] = *(const short8*)&Bs[cur][(wn * 128 + nt * 16 + lm) * 32 + quad * 8];
#pragma unroll
        for (int mt = 0; mt < 4; ++mt)
#pragma unroll
            for (int nt = 0; nt < 8; ++nt)
                acc[mt][nt] = __builtin_amdgcn_mfma_f32_16x16x32_bf16(
                    af[mt], bf[nt], acc[mt][nt], 0, 0, 0);

        if (has2) { asm volatile("s_waitcnt vmcnt(6)" ::: "memory"); }
        else      { asm volatile("s_waitcnt vmcnt(0)" ::: "memory"); }
        __builtin_amdgcn_sched_barrier(0);
        __builtin_amdgcn_s_barrier();
        cur = (cur == 2) ? 0 : cur + 1;
    }

#pragma unroll
    for (int mt = 0; mt < 4; ++mt)
#pragma unroll
        for (int r = 0; r < 4; ++r) {
            const size_t row = rowC + wm * 64 + mt * 16 + quad * 4 + r;
#pragma unroll
            for (int nt = 0; nt < 8; ++nt) {
                const size_t col = colC + wn * 128 + nt * 16 + lm;
                if (OUTF32) ((float*)C)[row * N + col] = acc[mt][nt][r];
                else        ((ushort_t*)C)[row * N + col] = f2bf(acc[mt][nt][r]);
            }
        }
}

// ---------------------------------------------------------------------------
// GEMM1 with fused rope+rmsnorm epilogue on q/k; v written transposed to
// vtb[(b*CC + h*64 + d)][t]. 128x256 tile; each wave's 128 cols = 2 heads.
// ---------------------------------------------------------------------------
__global__ __launch_bounds__(256) void gemm_qkv(const ushort_t* __restrict__ A,
                                                const ushort_t* __restrict__ B,
                                                ushort_t* __restrict__ C,
                                                ushort_t* __restrict__ vtb,
                                                const float* __restrict__ cosb,
                                                const float* __restrict__ sinb,
                                                int M, int N, int K) {
    __shared__ ushort_t As[3][128 * 32];
    __shared__ ushort_t Bs[3][256 * 32];

    const int tid  = threadIdx.x;
    const int wv   = tid >> 6;
    const int ln   = tid & 63;
    const int quad = ln >> 4;
    const int lm   = ln & 15;
    const int wm   = wv & 1;
    const int wn   = wv >> 1;
    const int rowC = blockIdx.y * 128;
    const int colC = blockIdx.x * 256;

    const int srow = wv * 16 + (ln >> 2);
    const int skq  = (ln & 3) * 8;

    f32x4 acc[4][8];
#pragma unroll
    for (int i = 0; i < 4; ++i)
#pragma unroll
        for (int j = 0; j < 8; ++j) acc[i][j] = (f32x4){0.f, 0.f, 0.f, 0.f};

    auto stage = [&](int k0, int bufi) {
#pragma unroll
        for (int half = 0; half < 2; ++half) {
            const ushort_t* gA = A + (size_t)(rowC + half * 64 + srow) * K + k0 + skq;
            GLOAD_LDS(gA, As[bufi] + (half * 64 + wv * 16) * 32);
        }
#pragma unroll
        for (int qtr = 0; qtr < 4; ++qtr) {
            const ushort_t* gB = B + (size_t)(colC + qtr * 64 + srow) * K + k0 + skq;
            GLOAD_LDS(gB, Bs[bufi] + (qtr * 64 + wv * 16) * 32);
        }
    };

    const int nk = K >> 5;
    stage(0, 0);
    stage(32, 1);
    asm volatile("s_waitcnt vmcnt(6)" ::: "memory");
    __builtin_amdgcn_sched_barrier(0);
    __builtin_amdgcn_s_barrier();

    int cur = 0;
    for (int ki = 0; ki < nk; ++ki) {
        const bool has2 = (ki + 2 < nk);
        if (has2) {
            int b2 = cur + 2; if (b2 >= 3) b2 -= 3;
            stage((ki + 2) << 5, b2);
        }

        short8 af[4], bf[8];
#pragma unroll
        for (int mt = 0; mt < 4; ++mt)
            af[mt] = *(const short8*)&As[cur][(wm * 64 + mt * 16 + lm) * 32 + quad * 8];
#pragma unroll
        for (int nt = 0; nt < 8; ++nt)
            bf[nt] = *(const short8*)&Bs[cur][(wn * 128 + nt * 16 + lm) * 32 + quad * 8];
#pragma unroll
        for (int mt = 0; mt < 4; ++mt)
#pragma unroll
            for (int nt = 0; nt < 8; ++nt)
                acc[mt][nt] = __builtin_amdgcn_mfma_f32_16x16x32_bf16(
                    af[mt], bf[nt], acc[mt][nt], 0, 0, 0);

        if (has2) { asm volatile("s_waitcnt vmcnt(6)" ::: "memory"); }
        else      { asm volatile("s_waitcnt vmcnt(0)" ::: "memory"); }
        __builtin_amdgcn_sched_barrier(0);
        __builtin_amdgcn_s_barrier();
        cur = (cur == 2) ? 0 : cur + 1;
    }

    const bool isqk = colC < 2 * CC;   // q or k section (tile never straddles)
    if (isqk) {
#pragma unroll
        for (int mt = 0; mt < 4; ++mt)
#pragma unroll
            for (int r = 0; r < 4; ++r) {
                const int row = rowC + wm * 64 + mt * 16 + quad * 4 + r;
                ushort_t* Cp = C + (size_t)row * N + colC + wn * 128 + lm;
                const int t = row & (TT - 1);
                // two heads per wave: nt 0..3 (head A), nt 4..7 (head B)
                float ssA = 0.f, ssB = 0.f;
#pragma unroll
                for (int nt = 0; nt < 4; ++nt) {
                    ssA += acc[mt][nt][r] * acc[mt][nt][r];
                    ssB += acc[mt][nt + 4][r] * acc[mt][nt + 4][r];
                }
                ssA += __shfl_xor(ssA, 1); ssB += __shfl_xor(ssB, 1);
                ssA += __shfl_xor(ssA, 2); ssB += __shfl_xor(ssB, 2);
                ssA += __shfl_xor(ssA, 4); ssB += __shfl_xor(ssB, 4);
                ssA += __shfl_xor(ssA, 8); ssB += __shfl_xor(ssB, 8);
                const float rinvA = rsqrtf(ssA * (1.0f / 64.0f) + 1e-6f);
                const float rinvB = rsqrtf(ssB * (1.0f / 64.0f) + 1e-6f);
                const float c0 = cosb[t * 32 + lm];
                const float c1 = cosb[t * 32 + 16 + lm];
                const float s0 = sinb[t * 32 + lm];
                const float s1 = sinb[t * 32 + 16 + lm];
                // head A
                Cp[0]  = f2bf((acc[mt][0][r] * c0 + acc[mt][2][r] * s0) * rinvA);
                Cp[16] = f2bf((acc[mt][1][r] * c1 + acc[mt][3][r] * s1) * rinvA);
                Cp[32] = f2bf((acc[mt][2][r] * c0 - acc[mt][0][r] * s0) * rinvA);
                Cp[48] = f2bf((acc[mt][3][r] * c1 - acc[mt][1][r] * s1) * rinvA);
                // head B
                Cp[64]  = f2bf((acc[mt][4][r] * c0 + acc[mt][6][r] * s0) * rinvB);
                Cp[80]  = f2bf((acc[mt][5][r] * c1 + acc[mt][7][r] * s1) * rinvB);
                Cp[96]  = f2bf((acc[mt][6][r] * c0 - acc[mt][4][r] * s0) * rinvB);
                Cp[112] = f2bf((acc[mt][7][r] * c1 - acc[mt][5][r] * s1) * rinvB);
            }
    } else {
        // v: write transposed. Lane's 4 r-values are 4 consecutive t at one
        // (h,d) row -> one packed 8B store each nt.
#pragma unroll
        for (int mt = 0; mt < 4; ++mt) {
            const int row0 = rowC + wm * 64 + mt * 16 + quad * 4;
            const int bb = row0 >> 11;         // batch
            const int tt = row0 & (TT - 1);    // t of r=0
#pragma unroll
            for (int nt = 0; nt < 8; ++nt) {
                const int hd = colC - 2 * CC + wn * 128 + nt * 16 + lm;
                short4_t pk;
                pk[0] = (short)f2bf(acc[mt][nt][0]);
                pk[1] = (short)f2bf(acc[mt][nt][1]);
                pk[2] = (short)f2bf(acc[mt][nt][2]);
                pk[3] = (short)f2bf(acc[mt][nt][3]);
                *(short4_t*)(vtb + (size_t)(bb * CC + hd) * TT + tt) = pk;
            }
        }
    }
}

// ---------------------------------------------------------------------------
// bf16 MFMA flash attention, fixed-max softmax, QBLK=128 per block.
// (unchanged from round 7/9/10 — passing, no spills)
// ---------------------------------------------------------------------------
__global__ __launch_bounds__(256, 3) void attn_mfma(ushort_t* __restrict__ qkv,
                                                    const ushort_t* __restrict__ vt) {
    const int bx = blockIdx.x;             // 0..1023, flat
    const int c  = 15 - (bx >> 6);         // q-chunk 0..15, longest first
    const int hb = bx & 63;
    const int h  = hb & 15;
    const int b  = hb >> 4;
    const int tid  = threadIdx.x;
    const int w    = tid >> 6;
    const int lane = tid & 63;
    const int quad = lane >> 4;
    const int lm   = lane & 15;

    __shared__ ushort_t Ks[2][64][72];     // K[n][d]
    __shared__ ushort_t Vs[2][64][72];     // V^T[d][kappa], kappa = pi-permuted k

    // q fragments: wave w owns q rows c*128 + w*32 + qs*16 + lm (qs=0,1)
    short8 qf[2][2];
#pragma unroll
    for (int qs = 0; qs < 2; ++qs) {
        const ushort_t* qa = qkv + (size_t)(b * TT + c * 128 + w * 32 + qs * 16 + lm) * (3 * CC) + h * DD;
        qf[qs][0] = *(const short8*)(qa + quad * 8);
        qf[qs][1] = *(const short8*)(qa + 32 + quad * 8);
    }

    f32x4 O[2][4];
    f32x4 lac[2];
#pragma unroll
    for (int qs = 0; qs < 2; ++qs) {
        lac[qs] = (f32x4){0.f, 0.f, 0.f, 0.f};
#pragma unroll
        for (int dt = 0; dt < 4; ++dt) O[qs][dt] = (f32x4){0.f, 0.f, 0.f, 0.f};
    }

    const short one_bf = (short)0x3F80;    // bf16 1.0
    const short8 vones = {one_bf, one_bf, one_bf, one_bf, one_bf, one_bf, one_bf, one_bf};

    // staging indices
    const int sn = tid >> 2;               // K row (t) / V row (d)
    const int si = tid & 3;
    const int sd = si * 16;
    // kappa base for the V permutation: k_phys 16*si+4q+r -> kappa kb+8q+r
    const int kb = ((si >> 1) << 5) + ((si & 1) << 2);

    short8 k0v, k1v, v0v, v1v;
    auto stage_load = [&](int kt) {
        const ushort_t* kp = qkv + (size_t)(b * TT + kt * 64 + sn) * (3 * CC) + CC + h * DD + sd;
        k0v = *(const short8*)kp;
        k1v = *(const short8*)(kp + 8);
        const ushort_t* vp = vt + (size_t)(b * CC + h * DD + sn) * TT + kt * 64 + sd;
        v0v = *(const short8*)vp;
        v1v = *(const short8*)(vp + 8);
    };
    auto stage_write = [&](int bufi) {
        *(short8*)&Ks[bufi][sn][sd]     = k0v;
        *(short8*)&Ks[bufi][sn][sd + 8] = k1v;
        *(short4_t*)&Vs[bufi][sn][kb]      = __builtin_shufflevector(v0v, v0v, 0, 1, 2, 3);
        *(short4_t*)&Vs[bufi][sn][kb + 8]  = __builtin_shufflevector(v0v, v0v, 4, 5, 6, 7);
        *(short4_t*)&Vs[bufi][sn][kb + 16] = __builtin_shufflevector(v1v, v1v, 0, 1, 2, 3);
        *(short4_t*)&Vs[bufi][sn][kb + 24] = __builtin_shufflevector(v1v, v1v, 4, 5, 6, 7);
    };

    const int ktmax = 2 * c + 1;           // block's last kv tile
    const int ktw   = 2 * c + (w >> 1);    // this wave's diagonal tile
    const int qoff  = (w & 1) * 32;        // wave's q offset within diag tile

    // prologue: stage tile 0
    stage_load(0);
    stage_write(0);
    __syncthreads();

    int cur = 0;
    for (int kt = 0; kt <= ktmax; ++kt) {
        if (kt < ktmax) stage_load(kt + 1);    // issue next-tile globals early

        if (kt <= ktw) {
            // K / V fragments: register-resident, reused by both subtiles
            short8 kf[2][4], vf[2][4];
#pragma unroll
            for (int kk = 0; kk < 2; ++kk)
#pragma unroll
                for (int i = 0; i < 4; ++i) {
                    kf[kk][i] = *(const short8*)&Ks[cur][i * 16 + lm][kk * 32 + quad * 8];
                    vf[kk][i] = *(const short8*)&Vs[cur][i * 16 + lm][kk * 32 + quad * 8];
                }
            const bool diag = (kt == ktw);

#pragma unroll
            for (int qs = 0; qs < 2; ++qs) {
                // S^T = K @ Q^T : sf[i][r] = S[k=16i+quad*4+r][q=qs*16+lm]
                f32x4 sf[4];
#pragma unroll
                for (int i = 0; i < 4; ++i) sf[i] = (f32x4){0.f, 0.f, 0.f, 0.f};
#pragma unroll
                for (int kk = 0; kk < 2; ++kk)
#pragma unroll
                    for (int i = 0; i < 4; ++i)
                        sf[i] = __builtin_amdgcn_mfma_f32_16x16x32_bf16(
                            kf[kk][i], qf[qs][kk], sf[i], 0, 0, 0);

                // exp + pack (plain f2bf): lane's own p values ARE its PV
                // A-fragment under the pi relabeling: pa[kk][(i&1)*4+r]
                short8 pa0 = {0, 0, 0, 0, 0, 0, 0, 0};
                short8 pa1 = {0, 0, 0, 0, 0, 0, 0, 0};
#pragma unroll
                for (int i = 0; i < 4; ++i)
#pragma unroll
                    for (int r = 0; r < 4; ++r) {
                        const float s = fmaf(sf[i][r], 0.125f, -8.0f);
                        float p = __expf(s);   // scores in [-8,8] after rmsnorm
                        if (diag) {
                            const int kloc = i * 16 + quad * 4 + r;
                            p = (kloc <= qoff + qs * 16 + lm) ? p : 0.0f;
                        }
                        const short pb = (short)f2bf(p);
                        if (i < 2) pa0[(i & 1) * 4 + r] = pb;
                        else       pa1[(i & 1) * 4 + r] = pb;
                    }

                // PV: O[q][d] += P[q][pi(kappa)] * V[pi(kappa)][d]; l via ones
#pragma unroll
                for (int dt = 0; dt < 4; ++dt)
                    O[qs][dt] = __builtin_amdgcn_mfma_f32_16x16x32_bf16(
                        pa0, vf[0][dt], O[qs][dt], 0, 0, 0);
                lac[qs] = __builtin_amdgcn_mfma_f32_16x16x32_bf16(
                    pa0, vones, lac[qs], 0, 0, 0);
#pragma unroll
                for (int dt = 0; dt < 4; ++dt)
                    O[qs][dt] = __builtin_amdgcn_mfma_f32_16x16x32_bf16(
                        pa1, vf[1][dt], O[qs][dt], 0, 0, 0);
                lac[qs] = __builtin_amdgcn_mfma_f32_16x16x32_bf16(
                    pa1, vones, lac[qs], 0, 0, 0);
            }
        }

        if (kt < ktmax) stage_write(cur ^ 1);
        __syncthreads();
        cur ^= 1;
    }

    // epilogue: O row (quad*4+r) matches lac row; no cross-lane reduce needed
#pragma unroll
    for (int qs = 0; qs < 2; ++qs)
#pragma unroll
        for (int r = 0; r < 4; ++r) {
            const float inv_l = 1.0f / lac[qs][r];
            ushort_t* yp = qkv + (size_t)(b * TT + c * 128 + w * 32 + qs * 16 + quad * 4 + r) * (3 * CC)
                               + 2 * CC + h * DD + lm;
#pragma unroll
            for (int dt = 0; dt < 4; ++dt) yp[dt * 16] = f2bf(O[qs][dt][r] * inv_l);
        }
}

// ---------------------------------------------------------------------------
extern "C" void kernel_launch(void* const* d_in, const int* in_sizes, int n_in,
                              void* d_out, int out_size, void* d_ws, size_t ws_size,
                              hipStream_t stream) {
    const float* x      = (const float*)d_in[0];   // (4,2048,1024)
    const float* cosb   = (const float*)d_in[1];   // (1,2048,1,32)
    const float* sinb   = (const float*)d_in[2];
    const float* w_attn = (const float*)d_in[3];   // (3072,1024)
    const float* w_proj = (const float*)d_in[4];   // (1024,1024)
    float* out = (float*)d_out;                    // (4,2048,1024)

    // workspace layout (bf16 elements)
    ushort_t* qkvb = (ushort_t*)d_ws;                       // 8192*3072 (q,k; v-cols hold y)
    ushort_t* vtb  = qkvb + (size_t)8192 * 3072;            // 4096*2048 = 8192*1024 (V^T)
    ushort_t* xb   = vtb  + (size_t)8192 * 1024;            // 8192*1024
    ushort_t* wab  = xb   + (size_t)8192 * 1024;            // 3072*1024
    ushort_t* wpb  = wab  + (size_t)3072 * 1024;            // 1024*1024

    cast_bf16<<<(8192 * 1024 / 8 + 255) / 256, 256, 0, stream>>>(x, xb, 8192 * 1024 / 8);
    cast_bf16<<<(3072 * 1024 / 8 + 255) / 256, 256, 0, stream>>>(w_attn, wab, 3072 * 1024 / 8);
    cast_bf16<<<(1024 * 1024 / 8 + 255) / 256, 256, 0, stream>>>(w_proj, wpb, 1024 * 1024 / 8);

    // qkv = x @ w_attn^T; rope+rmsnorm on q,k; v transposed into vtb
    gemm_qkv<<<dim3(3072 / 256, 8192 / 128), 256, 0, stream>>>(
        xb, wab, qkvb, vtb, cosb, sinb, 8192, 3072, 1024);

    // causal attention -> y into qkvb's v-columns (QBLK=128, flat LPT grid)
    attn_mfma<<<dim3(1024, 1, 1), 256, 0, stream>>>(qkvb, vtb);

    // out = y @ w_proj^T (fp32 out), A = qkvb v-columns with lda=3072
    gemm_bt<true><<<dim3(1024 / 256, 8192 / 128), 256, 0, stream>>>(
        qkvb + 2 * CC, wpb, out, 8192, 1024, 1024, 3 * CC);
}

// Round 12
// 248.891 us; speedup vs baseline: 1.2226x; 1.2226x over previous
//
#include <hip/hip_runtime.h>
#include <hip/hip_bf16.h>
#include <math.h>

// Problem: B=4, T=2048, C=1024, H=16, D=64, d_half=32
// Dataflow:
//   cast3: ONE kernel casts x, w_attn, w_proj -> bf16 (was 3 launches;
//          ~10us/dispatch overhead observed across rounds)
//   qkvb = xb @ wab^T  rope+rmsnorm fused into q/k epilogue; v written
//          PRE-TRANSPOSED to vt[b*C + h*64 + d][t] (packed short4 over r)
//   attn (bf16 MFMA flash, fixed-max softmax): QBLK=128/block, swapped
//          QK^T keeps P in registers, ones-column row sums, dbuf staging,
//          launch_bounds(256,3); + s_setprio(1) around compute cluster.
//   out  = (qkvb v-cols as y, lda=3072) @ wpb^T  (fp32 out)
//   BOTH GEMMs: R10 structure (128x128 tile, 3-buffer 2-deep prefetch,
//   counted vmcnt(4)) — R11's 128x256 tile regressed (2 blocks/CU).

#define TT 2048
#define CC 1024
#define HH 16
#define DD 64

typedef __attribute__((ext_vector_type(8))) short short8;
typedef __attribute__((ext_vector_type(4))) short short4_t;
typedef __attribute__((ext_vector_type(4))) float f32x4;
typedef unsigned short ushort_t;

// fp32 -> bf16 (RNE, finite inputs only)
__device__ __forceinline__ ushort_t f2bf(float f) {
    unsigned u = __builtin_bit_cast(unsigned, f);
    u = (u + 0x7fffu + ((u >> 16) & 1u)) >> 16;
    return (ushort_t)u;
}

#define GLOAD_LDS(gp, lp)                                                      \
    __builtin_amdgcn_global_load_lds(                                          \
        (const __attribute__((address_space(1))) unsigned int*)(gp),           \
        (__attribute__((address_space(3))) unsigned int*)(lp), 16, 0, 0)

// ---------------------------------------------------------------------------
// fused float -> bf16 cast for three arrays, 8 elements/thread
// ---------------------------------------------------------------------------
__global__ __launch_bounds__(256) void cast3_bf16(const float* __restrict__ in0,
                                                  ushort_t* __restrict__ out0, int n0,
                                                  const float* __restrict__ in1,
                                                  ushort_t* __restrict__ out1, int n1,
                                                  const float* __restrict__ in2,
                                                  ushort_t* __restrict__ out2, int n2) {
    int i = blockIdx.x * 256 + threadIdx.x;
    const float* in;
    ushort_t* out;
    if (i < n0) { in = in0; out = out0; }
    else if (i < n0 + n1) { i -= n0; in = in1; out = out1; }
    else if (i < n0 + n1 + n2) { i -= n0 + n1; in = in2; out = out2; }
    else return;
    const float4* p = (const float4*)in + (size_t)i * 2;
    float4 f0 = p[0], f1 = p[1];
    short8 v;
    v[0] = (short)f2bf(f0.x); v[1] = (short)f2bf(f0.y);
    v[2] = (short)f2bf(f0.z); v[3] = (short)f2bf(f0.w);
    v[4] = (short)f2bf(f1.x); v[5] = (short)f2bf(f1.y);
    v[6] = (short)f2bf(f1.z); v[7] = (short)f2bf(f1.w);
    *(short8*)(out + (size_t)i * 8) = v;
}

// ---------------------------------------------------------------------------
// bf16 MFMA GEMM: C = A[M,K](lda) * B[N,K]^T, 128x128 tile, BK=32.
// 3-buffer 2-deep prefetch, counted vmcnt(4), raw s_barrier. (R10 proven)
// ---------------------------------------------------------------------------
template <bool OUTF32>
__global__ __launch_bounds__(256) void gemm_bt(const ushort_t* __restrict__ A,
                                               const ushort_t* __restrict__ B,
                                               void* __restrict__ C,
                                               int M, int N, int K, int lda) {
    __shared__ ushort_t As[3][128 * 32];
    __shared__ ushort_t Bs[3][128 * 32];

    const int tid  = threadIdx.x;
    const int wv   = tid >> 6;
    const int ln   = tid & 63;
    const int quad = ln >> 4;
    const int lm   = ln & 15;
    const int wm   = wv & 1;
    const int wn   = wv >> 1;
    const int rowC = blockIdx.y * 128;
    const int colC = blockIdx.x * 128;

    const int srow = wv * 16 + (ln >> 2);
    const int skq  = (ln & 3) * 8;

    f32x4 acc[4][4];
#pragma unroll
    for (int i = 0; i < 4; ++i)
#pragma unroll
        for (int j = 0; j < 4; ++j) acc[i][j] = (f32x4){0.f, 0.f, 0.f, 0.f};

    // 4 global_load_lds per thread per stage
    auto stage = [&](int k0, int bufi) {
#pragma unroll
        for (int half = 0; half < 2; ++half) {
            const ushort_t* gA = A + (size_t)(rowC + half * 64 + srow) * lda + k0 + skq;
            const ushort_t* gB = B + (size_t)(colC + half * 64 + srow) * K + k0 + skq;
            GLOAD_LDS(gA, As[bufi] + (half * 64 + wv * 16) * 32);
            GLOAD_LDS(gB, Bs[bufi] + (half * 64 + wv * 16) * 32);
        }
    };

    const int nk = K >> 5;
    stage(0, 0);
    stage(32, 1);
    asm volatile("s_waitcnt vmcnt(4)" ::: "memory");   // stage 0 complete
    __builtin_amdgcn_sched_barrier(0);
    __builtin_amdgcn_s_barrier();

    int cur = 0;
    for (int ki = 0; ki < nk; ++ki) {
        const bool has2 = (ki + 2 < nk);
        if (has2) {
            int b2 = cur + 2; if (b2 >= 3) b2 -= 3;
            stage((ki + 2) << 5, b2);                  // issue 2-ahead
        }

        short8 af[4], bf[4];
#pragma unroll
        for (int mt = 0; mt < 4; ++mt)
            af[mt] = *(const short8*)&As[cur][(wm * 64 + mt * 16 + lm) * 32 + quad * 8];
#pragma unroll
        for (int nt = 0; nt < 4; ++nt)
            bf[nt] = *(const short8*)&Bs[cur][(wn * 64 + nt * 16 + lm) * 32 + quad * 8];
#pragma unroll
        for (int mt = 0; mt < 4; ++mt)
#pragma unroll
            for (int nt = 0; nt < 4; ++nt)
                acc[mt][nt] = __builtin_amdgcn_mfma_f32_16x16x32_bf16(
                    af[mt], bf[nt], acc[mt][nt], 0, 0, 0);

        // next tile ready: keep the 2-ahead stage (4 loads) in flight
        if (has2) { asm volatile("s_waitcnt vmcnt(4)" ::: "memory"); }
        else      { asm volatile("s_waitcnt vmcnt(0)" ::: "memory"); }
        __builtin_amdgcn_sched_barrier(0);
        __builtin_amdgcn_s_barrier();
        cur = (cur == 2) ? 0 : cur + 1;
    }

#pragma unroll
    for (int mt = 0; mt < 4; ++mt)
#pragma unroll
        for (int r = 0; r < 4; ++r) {
            const size_t row = rowC + wm * 64 + mt * 16 + quad * 4 + r;
#pragma unroll
            for (int nt = 0; nt < 4; ++nt) {
                const size_t col = colC + wn * 64 + nt * 16 + lm;
                if (OUTF32) ((float*)C)[row * N + col] = acc[mt][nt][r];
                else        ((ushort_t*)C)[row * N + col] = f2bf(acc[mt][nt][r]);
            }
        }
}

// ---------------------------------------------------------------------------
// GEMM1 with fused rope+rmsnorm epilogue on q/k; v written transposed to
// vtb[(b*CC + h*64 + d)][t] as packed short4. Same 3-buffer counted-vmcnt loop.
// ---------------------------------------------------------------------------
__global__ __launch_bounds__(256) void gemm_qkv(const ushort_t* __restrict__ A,
                                                const ushort_t* __restrict__ B,
                                                ushort_t* __restrict__ C,
                                                ushort_t* __restrict__ vtb,
                                                const float* __restrict__ cosb,
                                                const float* __restrict__ sinb,
                                                int M, int N, int K) {
    __shared__ ushort_t As[3][128 * 32];
    __shared__ ushort_t Bs[3][128 * 32];

    const int tid  = threadIdx.x;
    const int wv   = tid >> 6;
    const int ln   = tid & 63;
    const int quad = ln >> 4;
    const int lm   = ln & 15;
    const int wm   = wv & 1;
    const int wn   = wv >> 1;
    const int rowC = blockIdx.y * 128;
    const int colC = blockIdx.x * 128;

    const int srow = wv * 16 + (ln >> 2);
    const int skq  = (ln & 3) * 8;

    f32x4 acc[4][4];
#pragma unroll
    for (int i = 0; i < 4; ++i)
#pragma unroll
        for (int j = 0; j < 4; ++j) acc[i][j] = (f32x4){0.f, 0.f, 0.f, 0.f};

    auto stage = [&](int k0, int bufi) {
#pragma unroll
        for (int half = 0; half < 2; ++half) {
            const ushort_t* gA = A + (size_t)(rowC + half * 64 + srow) * K + k0 + skq;
            const ushort_t* gB = B + (size_t)(colC + half * 64 + srow) * K + k0 + skq;
            GLOAD_LDS(gA, As[bufi] + (half * 64 + wv * 16) * 32);
            GLOAD_LDS(gB, Bs[bufi] + (half * 64 + wv * 16) * 32);
        }
    };

    const int nk = K >> 5;
    stage(0, 0);
    stage(32, 1);
    asm volatile("s_waitcnt vmcnt(4)" ::: "memory");
    __builtin_amdgcn_sched_barrier(0);
    __builtin_amdgcn_s_barrier();

    int cur = 0;
    for (int ki = 0; ki < nk; ++ki) {
        const bool has2 = (ki + 2 < nk);
        if (has2) {
            int b2 = cur + 2; if (b2 >= 3) b2 -= 3;
            stage((ki + 2) << 5, b2);
        }

        short8 af[4], bf[4];
#pragma unroll
        for (int mt = 0; mt < 4; ++mt)
            af[mt] = *(const short8*)&As[cur][(wm * 64 + mt * 16 + lm) * 32 + quad * 8];
#pragma unroll
        for (int nt = 0; nt < 4; ++nt)
            bf[nt] = *(const short8*)&Bs[cur][(wn * 64 + nt * 16 + lm) * 32 + quad * 8];
#pragma unroll
        for (int mt = 0; mt < 4; ++mt)
#pragma unroll
            for (int nt = 0; nt < 4; ++nt)
                acc[mt][nt] = __builtin_amdgcn_mfma_f32_16x16x32_bf16(
                    af[mt], bf[nt], acc[mt][nt], 0, 0, 0);

        if (has2) { asm volatile("s_waitcnt vmcnt(4)" ::: "memory"); }
        else      { asm volatile("s_waitcnt vmcnt(0)" ::: "memory"); }
        __builtin_amdgcn_sched_barrier(0);
        __builtin_amdgcn_s_barrier();
        cur = (cur == 2) ? 0 : cur + 1;
    }

    const bool isqk = colC < 2 * CC;   // q or k section
    if (isqk) {
#pragma unroll
        for (int mt = 0; mt < 4; ++mt)
#pragma unroll
            for (int r = 0; r < 4; ++r) {
                const int row = rowC + wm * 64 + mt * 16 + quad * 4 + r;
                ushort_t* Cp = C + (size_t)row * N + colC + wn * 64 + lm;
                const int t = row & (TT - 1);
                float ss = 0.f;
#pragma unroll
                for (int nt = 0; nt < 4; ++nt) ss += acc[mt][nt][r] * acc[mt][nt][r];
                ss += __shfl_xor(ss, 1);
                ss += __shfl_xor(ss, 2);
                ss += __shfl_xor(ss, 4);
                ss += __shfl_xor(ss, 8);
                const float rinv = rsqrtf(ss * (1.0f / 64.0f) + 1e-6f);
                const float c0 = cosb[t * 32 + lm];
                const float c1 = cosb[t * 32 + 16 + lm];
                const float s0 = sinb[t * 32 + lm];
                const float s1 = sinb[t * 32 + 16 + lm];
                const float o0 = acc[mt][0][r] * c0 + acc[mt][2][r] * s0;
                const float o1 = acc[mt][1][r] * c1 + acc[mt][3][r] * s1;
                const float o2 = acc[mt][2][r] * c0 - acc[mt][0][r] * s0;
                const float o3 = acc[mt][3][r] * c1 - acc[mt][1][r] * s1;
                Cp[0]  = f2bf(o0 * rinv);
                Cp[16] = f2bf(o1 * rinv);
                Cp[32] = f2bf(o2 * rinv);
                Cp[48] = f2bf(o3 * rinv);
            }
    } else {
        // v: write transposed. Lane's 4 r-values are 4 consecutive t at one
        // (h,d) row -> one packed 8B store each nt.
#pragma unroll
        for (int mt = 0; mt < 4; ++mt) {
            const int row0 = rowC + wm * 64 + mt * 16 + quad * 4;
            const int bb = row0 >> 11;         // batch
            const int tt = row0 & (TT - 1);    // t of r=0
#pragma unroll
            for (int nt = 0; nt < 4; ++nt) {
                const int hd = colC - 2 * CC + wn * 64 + nt * 16 + lm;
                short4_t pk;
                pk[0] = (short)f2bf(acc[mt][nt][0]);
                pk[1] = (short)f2bf(acc[mt][nt][1]);
                pk[2] = (short)f2bf(acc[mt][nt][2]);
                pk[3] = (short)f2bf(acc[mt][nt][3]);
                *(short4_t*)(vtb + (size_t)(bb * CC + hd) * TT + tt) = pk;
            }
        }
    }
}

// ---------------------------------------------------------------------------
// bf16 MFMA flash attention, fixed-max softmax, QBLK=128 per block.
// R7 structure + s_setprio(1/0) around the compute cluster (T5; isolated —
// R4's failure is attributed to the removed inline-asm packing, not setprio).
// ---------------------------------------------------------------------------
__global__ __launch_bounds__(256, 3) void attn_mfma(ushort_t* __restrict__ qkv,
                                                    const ushort_t* __restrict__ vt) {
    const int bx = blockIdx.x;             // 0..1023, flat
    const int c  = 15 - (bx >> 6);         // q-chunk 0..15, longest first
    const int hb = bx & 63;
    const int h  = hb & 15;
    const int b  = hb >> 4;
    const int tid  = threadIdx.x;
    const int w    = tid >> 6;
    const int lane = tid & 63;
    const int quad = lane >> 4;
    const int lm   = lane & 15;

    __shared__ ushort_t Ks[2][64][72];     // K[n][d]
    __shared__ ushort_t Vs[2][64][72];     // V^T[d][kappa], kappa = pi-permuted k

    // q fragments: wave w owns q rows c*128 + w*32 + qs*16 + lm (qs=0,1)
    short8 qf[2][2];
#pragma unroll
    for (int qs = 0; qs < 2; ++qs) {
        const ushort_t* qa = qkv + (size_t)(b * TT + c * 128 + w * 32 + qs * 16 + lm) * (3 * CC) + h * DD;
        qf[qs][0] = *(const short8*)(qa + quad * 8);
        qf[qs][1] = *(const short8*)(qa + 32 + quad * 8);
    }

    f32x4 O[2][4];
    f32x4 lac[2];
#pragma unroll
    for (int qs = 0; qs < 2; ++qs) {
        lac[qs] = (f32x4){0.f, 0.f, 0.f, 0.f};
#pragma unroll
        for (int dt = 0; dt < 4; ++dt) O[qs][dt] = (f32x4){0.f, 0.f, 0.f, 0.f};
    }

    const short one_bf = (short)0x3F80;    // bf16 1.0
    const short8 vones = {one_bf, one_bf, one_bf, one_bf, one_bf, one_bf, one_bf, one_bf};

    // staging indices
    const int sn = tid >> 2;               // K row (t) / V row (d)
    const int si = tid & 3;
    const int sd = si * 16;
    // kappa base for the V permutation: k_phys 16*si+4q+r -> kappa kb+8q+r
    const int kb = ((si >> 1) << 5) + ((si & 1) << 2);

    short8 k0v, k1v, v0v, v1v;
    auto stage_load = [&](int kt) {
        const ushort_t* kp = qkv + (size_t)(b * TT + kt * 64 + sn) * (3 * CC) + CC + h * DD + sd;
        k0v = *(const short8*)kp;
        k1v = *(const short8*)(kp + 8);
        const ushort_t* vp = vt + (size_t)(b * CC + h * DD + sn) * TT + kt * 64 + sd;
        v0v = *(const short8*)vp;
        v1v = *(const short8*)(vp + 8);
    };
    auto stage_write = [&](int bufi) {
        *(short8*)&Ks[bufi][sn][sd]     = k0v;
        *(short8*)&Ks[bufi][sn][sd + 8] = k1v;
        *(short4_t*)&Vs[bufi][sn][kb]      = __builtin_shufflevector(v0v, v0v, 0, 1, 2, 3);
        *(short4_t*)&Vs[bufi][sn][kb + 8]  = __builtin_shufflevector(v0v, v0v, 4, 5, 6, 7);
        *(short4_t*)&Vs[bufi][sn][kb + 16] = __builtin_shufflevector(v1v, v1v, 0, 1, 2, 3);
        *(short4_t*)&Vs[bufi][sn][kb + 24] = __builtin_shufflevector(v1v, v1v, 4, 5, 6, 7);
    };

    const int ktmax = 2 * c + 1;           // block's last kv tile
    const int ktw   = 2 * c + (w >> 1);    // this wave's diagonal tile
    const int qoff  = (w & 1) * 32;        // wave's q offset within diag tile

    // prologue: stage tile 0
    stage_load(0);
    stage_write(0);
    __syncthreads();

    int cur = 0;
    for (int kt = 0; kt <= ktmax; ++kt) {
        if (kt < ktmax) stage_load(kt + 1);    // issue next-tile globals early

        if (kt <= ktw) {
            // K / V fragments: register-resident, reused by both subtiles
            short8 kf[2][4], vf[2][4];
#pragma unroll
            for (int kk = 0; kk < 2; ++kk)
#pragma unroll
                for (int i = 0; i < 4; ++i) {
                    kf[kk][i] = *(const short8*)&Ks[cur][i * 16 + lm][kk * 32 + quad * 8];
                    vf[kk][i] = *(const short8*)&Vs[cur][i * 16 + lm][kk * 32 + quad * 8];
                }
            const bool diag = (kt == ktw);

            __builtin_amdgcn_s_setprio(1);
#pragma unroll
            for (int qs = 0; qs < 2; ++qs) {
                // S^T = K @ Q^T : sf[i][r] = S[k=16i+quad*4+r][q=qs*16+lm]
                f32x4 sf[4];
#pragma unroll
                for (int i = 0; i < 4; ++i) sf[i] = (f32x4){0.f, 0.f, 0.f, 0.f};
#pragma unroll
                for (int kk = 0; kk < 2; ++kk)
#pragma unroll
                    for (int i = 0; i < 4; ++i)
                        sf[i] = __builtin_amdgcn_mfma_f32_16x16x32_bf16(
                            kf[kk][i], qf[qs][kk], sf[i], 0, 0, 0);

                // exp + pack (plain f2bf): lane's own p values ARE its PV
                // A-fragment under the pi relabeling: pa[kk][(i&1)*4+r]
                short8 pa0 = {0, 0, 0, 0, 0, 0, 0, 0};
                short8 pa1 = {0, 0, 0, 0, 0, 0, 0, 0};
#pragma unroll
                for (int i = 0; i < 4; ++i)
#pragma unroll
                    for (int r = 0; r < 4; ++r) {
                        const float s = fmaf(sf[i][r], 0.125f, -8.0f);
                        float p = __expf(s);   // scores in [-8,8] after rmsnorm
                        if (diag) {
                            const int kloc = i * 16 + quad * 4 + r;
                            p = (kloc <= qoff + qs * 16 + lm) ? p : 0.0f;
                        }
                        const short pb = (short)f2bf(p);
                        if (i < 2) pa0[(i & 1) * 4 + r] = pb;
                        else       pa1[(i & 1) * 4 + r] = pb;
                    }

                // PV: O[q][d] += P[q][pi(kappa)] * V[pi(kappa)][d]; l via ones
#pragma unroll
                for (int dt = 0; dt < 4; ++dt)
                    O[qs][dt] = __builtin_amdgcn_mfma_f32_16x16x32_bf16(
                        pa0, vf[0][dt], O[qs][dt], 0, 0, 0);
                lac[qs] = __builtin_amdgcn_mfma_f32_16x16x32_bf16(
                    pa0, vones, lac[qs], 0, 0, 0);
#pragma unroll
                for (int dt = 0; dt < 4; ++dt)
                    O[qs][dt] = __builtin_amdgcn_mfma_f32_16x16x32_bf16(
                        pa1, vf[1][dt], O[qs][dt], 0, 0, 0);
                lac[qs] = __builtin_amdgcn_mfma_f32_16x16x32_bf16(
                    pa1, vones, lac[qs], 0, 0, 0);
            }
            __builtin_amdgcn_s_setprio(0);
        }

        if (kt < ktmax) stage_write(cur ^ 1);
        __syncthreads();
        cur ^= 1;
    }

    // epilogue: O row (quad*4+r) matches lac row; no cross-lane reduce needed
#pragma unroll
    for (int qs = 0; qs < 2; ++qs)
#pragma unroll
        for (int r = 0; r < 4; ++r) {
            const float inv_l = 1.0f / lac[qs][r];
            ushort_t* yp = qkv + (size_t)(b * TT + c * 128 + w * 32 + qs * 16 + quad * 4 + r) * (3 * CC)
                               + 2 * CC + h * DD + lm;
#pragma unroll
            for (int dt = 0; dt < 4; ++dt) yp[dt * 16] = f2bf(O[qs][dt][r] * inv_l);
        }
}

// ---------------------------------------------------------------------------
extern "C" void kernel_launch(void* const* d_in, const int* in_sizes, int n_in,
                              void* d_out, int out_size, void* d_ws, size_t ws_size,
                              hipStream_t stream) {
    const float* x      = (const float*)d_in[0];   // (4,2048,1024)
    const float* cosb   = (const float*)d_in[1];   // (1,2048,1,32)
    const float* sinb   = (const float*)d_in[2];
    const float* w_attn = (const float*)d_in[3];   // (3072,1024)
    const float* w_proj = (const float*)d_in[4];   // (1024,1024)
    float* out = (float*)d_out;                    // (4,2048,1024)

    // workspace layout (bf16 elements)
    ushort_t* qkvb = (ushort_t*)d_ws;                       // 8192*3072 (q,k; v-cols hold y)
    ushort_t* vtb  = qkvb + (size_t)8192 * 3072;            // 4096*2048 = 8192*1024 (V^T)
    ushort_t* xb   = vtb  + (size_t)8192 * 1024;            // 8192*1024
    ushort_t* wab  = xb   + (size_t)8192 * 1024;            // 3072*1024
    ushort_t* wpb  = wab  + (size_t)3072 * 1024;            // 1024*1024

    const int n0 = 8192 * 1024 / 8;   // x groups
    const int n1 = 3072 * 1024 / 8;   // w_attn groups
    const int n2 = 1024 * 1024 / 8;   // w_proj groups
    cast3_bf16<<<(n0 + n1 + n2 + 255) / 256, 256, 0, stream>>>(
        x, xb, n0, w_attn, wab, n1, w_proj, wpb, n2);

    // qkv = x @ w_attn^T; rope+rmsnorm on q,k; v transposed into vtb
    gemm_qkv<<<dim3(3072 / 128, 8192 / 128), 256, 0, stream>>>(
        xb, wab, qkvb, vtb, cosb, sinb, 8192, 3072, 1024);

    // causal attention -> y into qkvb's v-columns (QBLK=128, flat LPT grid)
    attn_mfma<<<dim3(1024, 1, 1), 256, 0, stream>>>(qkvb, vtb);

    // out = y @ w_proj^T (fp32 out), A = qkvb v-columns with lda=3072
    gemm_bt<true><<<dim3(1024 / 128, 8192 / 128), 256, 0, stream>>>(
        qkvb + 2 * CC, wpb, out, 8192, 1024, 1024, 3 * CC);
}